// Round 13
// baseline (658.659 us; speedup 1.0000x reference)
//
#include <hip/hip_runtime.h>
#include <hip/hip_bf16.h>

#define NN 6144
#define DD 64
#define NL 3
#define KK 24
#define BT2 128  // pair-tile dimension (xmat kernel)
#define KH2 16   // k-quarter staged at a time
#define MB 4     // rows per block (mlp kernel)
#define KCLAMP 7.99881172180175781f
#define BANDLO 7.0f   // x<=7.0 => tanh(x)<=1-1.66e-6; r(x)<=tanh+1e-6 < RB-7ulp

typedef unsigned long long ull;

// Bit-level emulation of XLA CPU f32 tanh, FMA variant. Verified bit-exact
// vs reference (rounds 2-12, absmax 0.0).
__device__ __forceinline__ float tanh_xla(float x) {
  float xc = fminf(fmaxf(x, -KCLAMP), KCLAMP);
  float x2 = xc * xc;
  float p = -2.76076847742355e-16f;
  p = fmaf(p, x2, 2.00018790482477e-13f);
  p = fmaf(p, x2, -8.60467152213735e-11f);
  p = fmaf(p, x2, 5.12229709037114e-08f);
  p = fmaf(p, x2, 1.48572235717979e-05f);
  p = fmaf(p, x2, 6.37261928875436e-04f);
  p = fmaf(p, x2, 4.89352455891786e-03f);
  p = xc * p;
  float q = 1.19825839466702e-06f;
  q = fmaf(q, x2, 1.18534705686654e-04f);
  q = fmaf(q, x2, 2.26843463243900e-03f);
  q = fmaf(q, x2, 4.89352518554385e-03f);
  float r = p / q;
  return (fabsf(x) < 0.0004f) ? x : r;
}

__device__ __forceinline__ ull shfl_xor_u64(ull v, int m) {
  unsigned lo = __shfl_xor((unsigned)v, m);
  unsigned hi = __shfl_xor((unsigned)(v >> 32), m);
  return ((ull)hi << 32) | lo;
}

// Kernel A: 3-layer tanh MLP chains (unchanged; bit-matches Eigen).
__global__ __launch_bounds__(256) void mlp_kernel(
    const int* __restrict__ idx, const float* __restrict__ scale_set,
    const float* __restrict__ emb1, const float* __restrict__ emb2,
    const float* __restrict__ W1, const float* __restrict__ b1,
    const float* __restrict__ W2, const float* __restrict__ b2,
    float* __restrict__ vt1, float* __restrict__ vt2) {
  __shared__ float Wt1[DD][DD];
  __shared__ float Wt2[DD][DD];
  __shared__ float bsh1[DD], bsh2[DD];
  __shared__ __align__(16) float o1sh[MB][DD];
  __shared__ __align__(16) float o2sh[MB][DD];
  const int t = threadIdx.x;
  const int r = t >> 6;
  const int j = t & 63;
  const int grow = blockIdx.x * MB + r;

  {
    int g = idx[grow];
    if (j < 16) {
      ((float4*)&o1sh[r][0])[j] = ((const float4*)(emb1 + (size_t)g * DD))[j];
      ((float4*)&o2sh[r][0])[j] = ((const float4*)(emb2 + (size_t)g * DD))[j];
    }
  }

  for (int l = 0; l < NL; ++l) {
    __syncthreads();
    {
      const float* w1p = W1 + ((size_t)l * DD + j) * DD + r * 16;
      const float* w2p = W2 + ((size_t)l * DD + j) * DD + r * 16;
#pragma unroll
      for (int w = 0; w < 4; ++w) {
        float4 a = *(const float4*)(w1p + 4 * w);
        float4 b = *(const float4*)(w2p + 4 * w);
        int k0 = r * 16 + 4 * w;
        Wt1[k0 + 0][j] = a.x; Wt1[k0 + 1][j] = a.y;
        Wt1[k0 + 2][j] = a.z; Wt1[k0 + 3][j] = a.w;
        Wt2[k0 + 0][j] = b.x; Wt2[k0 + 1][j] = b.y;
        Wt2[k0 + 2][j] = b.z; Wt2[k0 + 3][j] = b.w;
      }
    }
    if (t < DD) { bsh1[t] = b1[l * DD + t]; bsh2[t] = b2[l * DD + t]; }
    __syncthreads();

    const float s = scale_set[l];
    float a1 = 0.0f, a2 = 0.0f;
#pragma unroll
    for (int kb = 0; kb < 16; ++kb) {
      float4 s1 = ((const float4*)&o1sh[r][0])[kb];
      float4 s2 = ((const float4*)&o2sh[r][0])[kb];
      int k0 = 4 * kb;
      a1 = fmaf(s1.x * s, Wt1[k0 + 0][j], a1);
      a1 = fmaf(s1.y * s, Wt1[k0 + 1][j], a1);
      a1 = fmaf(s1.z * s, Wt1[k0 + 2][j], a1);
      a1 = fmaf(s1.w * s, Wt1[k0 + 3][j], a1);
      a2 = fmaf(s2.x * s, Wt2[k0 + 0][j], a2);
      a2 = fmaf(s2.y * s, Wt2[k0 + 1][j], a2);
      a2 = fmaf(s2.z * s, Wt2[k0 + 2][j], a2);
      a2 = fmaf(s2.w * s, Wt2[k0 + 3][j], a2);
    }
    float t1 = tanh_xla(3.0f * (a1 + bsh1[j]));
    float t2 = tanh_xla(3.0f * (a2 + bsh2[j]));
    __syncthreads();
    o1sh[r][j] = t1;
    o2sh[r][j] = t2;
    vt1[((size_t)l * DD + j) * NN + grow] = t1;
    vt2[((size_t)l * DD + j) * NN + grow] = t2;
  }
}

// Pass 1: antisymmetric pair-tile GEMM, 128x128 tile, 8x8 per-thread register
// tiles (unchanged from round 12; bit-exact mirror store).
__global__ __launch_bounds__(256) void xmat_kernel(
    const float* __restrict__ vt1, const float* __restrict__ vt2,
    float* __restrict__ out) {
  __shared__ float R1h[KH2][BT2];
  __shared__ float R2h[KH2][BT2];
  __shared__ float C1h[KH2][BT2];
  __shared__ float C2h[KH2][BT2];

  const int a = blockIdx.x;
  const int b = blockIdx.y;
  if (b < a) return;
  const int l = blockIdx.z;
  const int t = threadIdx.x;
  const int r0 = a * BT2;
  const int c0 = b * BT2;
  const float* w1 = vt1 + (size_t)l * DD * NN;
  const float* w2 = vt2 + (size_t)l * DD * NN;
  float* o = out + (size_t)l * NN * NN;

  const int ty = t >> 4;
  const int tx = t & 15;
  const int sk = t >> 4;
  const int sq = (t & 15) * 8;

  float acc1[8][8] = {{0.f}}, acc2[8][8] = {{0.f}};

#pragma unroll
  for (int h = 0; h < 4; ++h) {
    __syncthreads();
    {
      const size_t src = (size_t)(h * KH2 + sk) * NN;
      *(float4*)&R1h[sk][sq]     = *(const float4*)(w1 + src + r0 + sq);
      *(float4*)&R1h[sk][sq + 4] = *(const float4*)(w1 + src + r0 + sq + 4);
      *(float4*)&R2h[sk][sq]     = *(const float4*)(w2 + src + r0 + sq);
      *(float4*)&R2h[sk][sq + 4] = *(const float4*)(w2 + src + r0 + sq + 4);
      *(float4*)&C1h[sk][sq]     = *(const float4*)(w1 + src + c0 + sq);
      *(float4*)&C1h[sk][sq + 4] = *(const float4*)(w1 + src + c0 + sq + 4);
      *(float4*)&C2h[sk][sq]     = *(const float4*)(w2 + src + c0 + sq);
      *(float4*)&C2h[sk][sq + 4] = *(const float4*)(w2 + src + c0 + sq + 4);
    }
    __syncthreads();
#pragma unroll 2
    for (int kk = 0; kk < KH2; ++kk) {
      float r1[8], r2[8], c1[8], c2[8];
      *(float4*)&r1[0] = *(const float4*)&R1h[kk][8 * ty];
      *(float4*)&r1[4] = *(const float4*)&R1h[kk][8 * ty + 4];
      *(float4*)&r2[0] = *(const float4*)&R2h[kk][8 * ty];
      *(float4*)&r2[4] = *(const float4*)&R2h[kk][8 * ty + 4];
      *(float4*)&c1[0] = *(const float4*)&C1h[kk][8 * tx];
      *(float4*)&c1[4] = *(const float4*)&C1h[kk][8 * tx + 4];
      *(float4*)&c2[0] = *(const float4*)&C2h[kk][8 * tx];
      *(float4*)&c2[4] = *(const float4*)&C2h[kk][8 * tx + 4];
#pragma unroll
      for (int i = 0; i < 8; ++i)
#pragma unroll
        for (int j = 0; j < 8; ++j) {
          acc1[i][j] = fmaf(r1[i], c2[j], acc1[i][j]);  // v1_r . v2_c
          acc2[i][j] = fmaf(r2[i], c1[j], acc2[i][j]);  // v2_r . v1_c
        }
    }
  }

#pragma unroll
  for (int i = 0; i < 8; ++i) {
    float xv[8];
#pragma unroll
    for (int j = 0; j < 8; ++j) xv[j] = 3.0f * (acc1[i][j] - acc2[i][j]);
    float* p = o + (size_t)(r0 + 8 * ty + i) * NN + c0 + 8 * tx;
    *(float4*)p = *(float4*)&xv[0];
    *(float4*)(p + 4) = *(float4*)&xv[4];
  }
  if (b > a) {
#pragma unroll
    for (int j = 0; j < 8; ++j) {
      float xv[8];
#pragma unroll
      for (int i = 0; i < 8; ++i) xv[i] = 3.0f * (acc2[i][j] - acc1[i][j]);
      float* p = o + (size_t)(c0 + 8 * tx + j) * NN + r0 + 8 * ty;
      *(float4*)p = *(float4*)&xv[0];
      *(float4*)(p + 4) = *(float4*)&xv[4];
    }
  }
}

// Pass 2: one wave per row. Scan = CLASSIFY ONLY: plateau (x>=clamp) folds
// into a 96-bit RB mask; band entries (7.0,clamp) are COLLECTED (no tanh in
// the loop) into 8 named per-lane registers via a static select chain.
// Post-scan batch: <=8 tanh per lane in parallel; ==RB joins the RB masks,
// >RB becomes a super (2 slots). Census -> early-breaking ballot ranking ->
// butterfly super extraction -> zero+scatter (all verbatim round 12).
// FALLBACK (wave-uniform, rare: bcnt>8, scnt>=3, or RB total < 24-S):
// round-9 full-list machinery (validated absmax 0.0).
__global__ __launch_bounds__(256, 2) void topk_kernel(float* __restrict__ out) {
  const int t = threadIdx.x;
  const int w = t >> 6;
  const int lane = t & 63;
  const int row = blockIdx.x * 4 + w;     // layer*NN + row
  float* rp = out + (size_t)row * NN;
  const float Rclamp = tanh_xla(8.0f);    // exact plateau value (clamp)
  const unsigned RB = __float_as_uint(Rclamp);
  const ull KOFF = 1ull << 62;
  const ull lmask = (1ull << lane) - 1;

  ull rblo = 0ull, rbhi = 0ull;           // RB-class bit masks (bit e=sb*4+jj)
  ull bq0 = 0, bq1 = 0, bq2 = 0, bq3 = 0, // band candidates (x_bits<<32)|gidx
      bq4 = 0, bq5 = 0, bq6 = 0, bq7 = 0;
  unsigned bcnt = 0;

  float4 cur = *(const float4*)(rp + (size_t)lane * 4);
  for (int sb = 0; sb < 24; ++sb) {
    float4 nxt = cur;
    if (sb < 23) nxt = *(const float4*)(rp + (size_t)((sb + 1) * 64 + lane) * 4);
    const float* xp = (const float*)&cur;
    const unsigned gbase = (unsigned)(sb * 256 + lane * 4);

    unsigned nib = 0u;
#pragma unroll
    for (int jj = 0; jj < 4; ++jj) {
      float x = xp[jj];
      if (x >= KCLAMP) {
        nib |= 1u << jj;
      } else if (x > BANDLO) {
        ull key = ((ull)__float_as_uint(x) << 32) | (ull)(gbase + jj);
        bq7 = (bcnt == 7u) ? key : bq7;
        bq6 = (bcnt == 6u) ? key : bq6;
        bq5 = (bcnt == 5u) ? key : bq5;
        bq4 = (bcnt == 4u) ? key : bq4;
        bq3 = (bcnt == 3u) ? key : bq3;
        bq2 = (bcnt == 2u) ? key : bq2;
        bq1 = (bcnt == 1u) ? key : bq1;
        bq0 = (bcnt == 0u) ? key : bq0;
        ++bcnt;
      }
    }
    if (sb < 16) rblo |= ((ull)nib) << (sb * 4);
    else         rbhi |= ((ull)nib) << ((sb - 16) * 4);
    cur = nxt;
  }

  bool fb = (__ballot(bcnt > 8u) != 0ull);   // band overflow -> fallback

  // Batch band evaluation: all lanes in parallel, one slot at a time.
  ull sup0 = 0ull, sup1 = 0ull;
  unsigned scnt = 0;
#define PROC_BAND(I, BQ)                                                    \
  if (__any(bcnt > (I##u))) {                                               \
    bool has = bcnt > (I##u);                                               \
    float x = has ? __uint_as_float((unsigned)((BQ) >> 32)) : 0.0f;         \
    unsigned v = __float_as_uint(tanh_xla(x));                              \
    if (has) {                                                              \
      unsigned gidx = (unsigned)((BQ) & 0xFFFFull);                         \
      if (v == RB) {                                                        \
        unsigned e = ((gidx >> 8) << 2) | (gidx & 3u);                      \
        if (e < 64u) rblo |= 1ull << e;                                     \
        else         rbhi |= 1ull << (e - 64u);                             \
      } else if (v > RB) {                                                  \
        ull key = KOFF | ((ull)v << 32) | (ull)(0xFFFFu - gidx);            \
        if (scnt == 0u) sup0 = key;                                         \
        else if (scnt == 1u) sup1 = key;                                    \
        ++scnt;                                                             \
      }                                                                     \
    }                                                                       \
  }
  PROC_BAND(0, bq0)
  PROC_BAND(1, bq1)
  PROC_BAND(2, bq2)
  PROC_BAND(3, bq3)
  PROC_BAND(4, bq4)
  PROC_BAND(5, bq5)
  PROC_BAND(6, bq6)
  PROC_BAND(7, bq7)
#undef PROC_BAND

  // Super census (>2 on any lane -> fallback).
  fb = fb || (__ballot(scnt >= 3u) != 0ull);
  ull bs1 = __ballot(scnt >= 1u);
  ull bs2 = __ballot(scnt >= 2u);
  unsigned S = (unsigned)__popcll(bs1) + (unsigned)__popcll(bs2);
  unsigned E = (S < 24u) ? S : 24u;
  unsigned C24 = 24u - E;

  // Ranking pass over RB masks (typically breaks after step 0).
  ull klo = 0ull, khi = 0ull;
  if (!fb && C24 > 0u) {
    unsigned cum = 0;
    for (int sb = 0; sb < 24; ++sb) {
      unsigned nib = (unsigned)((sb < 16 ? (rblo >> (sb * 4))
                                         : (rbhi >> ((sb - 16) * 4))) & 15ull);
      ull bl0 = __ballot((nib & 1u) != 0u);
      ull bl1 = __ballot((nib & 2u) != 0u);
      ull bl2 = __ballot((nib & 4u) != 0u);
      ull bl3 = __ballot((nib & 8u) != 0u);
      unsigned below = (unsigned)__popcll(bl0 & lmask) +
                       (unsigned)__popcll(bl1 & lmask) +
                       (unsigned)__popcll(bl2 & lmask) +
                       (unsigned)__popcll(bl3 & lmask);
      unsigned base = cum + below;
#pragma unroll
      for (int jj = 0; jj < 4; ++jj) {
        if (nib & (1u << jj)) {
          unsigned rk = base + (unsigned)__builtin_popcount(nib & ((1u << jj) - 1u));
          if (rk < C24) {
            if (sb < 16) klo |= 1ull << (sb * 4 + jj);
            else         khi |= 1ull << ((sb - 16) * 4 + jj);
          }
        }
      }
      cum += (unsigned)__popcll(bl0) + (unsigned)__popcll(bl1) +
             (unsigned)__popcll(bl2) + (unsigned)__popcll(bl3);
      if (cum >= C24) break;   // wave-uniform; later ranks can't qualify
    }
    if (cum < C24) fb = true;  // not enough RB-class -> sub-RB would matter
  }

  if (!fb) {
    // Extract supers: e-th winner parked in lane e.
    float wv = 0.0f;
    int wi = 0;
    for (unsigned e = 0; e < E; ++e) {
      ull cand = (sup0 > sup1) ? sup0 : sup1;
      ull win = cand;
#pragma unroll
      for (int d = 1; d < 64; d <<= 1) {
        ull o2 = shfl_xor_u64(win, d);
        win = (o2 > win) ? o2 : win;
      }
      if (lane == (int)e) {
        wv = __uint_as_float((unsigned)((win >> 32) & 0x3FFFFFFFu));
        wi = 0xFFFF - (int)(win & 0xFFFFull);
      }
      if (sup0 == win) sup0 = 0ull;
      else if (sup1 == win) sup1 = 0ull;
    }
    // Zero the row, drain, scatter RB winners (Rclamp) + supers (own value).
    float4 z = make_float4(0.f, 0.f, 0.f, 0.f);
    for (int sb = 0; sb < 24; ++sb)
      *(float4*)(rp + (size_t)(sb * 64 + lane) * 4) = z;
    asm volatile("s_waitcnt vmcnt(0)" ::: "memory");
    while (klo) {
      int e = __builtin_ctzll(klo);
      rp[(e >> 2) * 256 + lane * 4 + (e & 3)] = Rclamp;
      klo &= klo - 1;
    }
    while (khi) {
      int e = __builtin_ctzll(khi);
      rp[(16 + (e >> 2)) * 256 + lane * 4 + (e & 3)] = Rclamp;
      khi &= khi - 1;
    }
    if (lane < (int)E && wv > 0.0f) rp[wi] = wv;
    return;
  }

  // FALLBACK: round-9 full-list scan + merge extraction (exact, validated).
  {
    const ull RKEYHI = (ull)RB << 32;
    const double EMPTYD = __longlong_as_double((long long)KOFF);
    ull mlo = 0ull, mhi = 0ull;   // plateau (x>=clamp) slot masks
    double s[KK];
#pragma unroll
    for (int q = 0; q < KK; ++q) s[q] = EMPTYD;
    ull s0k = KOFF;

    for (int sb = 0; sb < 24; ++sb) {
      float4 x4 = *(const float4*)(rp + (size_t)(sb * 64 + lane) * 4);
      const float* xp = (const float*)&x4;
      const unsigned gbase = (unsigned)(sb * 256 + lane * 4);
      unsigned nib = 0u;
#pragma unroll
      for (int jj = 0; jj < 4; ++jj) {
        float x = xp[jj];
        if (x >= KCLAMP) {
          nib |= 1u << jj;
        } else if (x > 0.0f) {
          float tv = tanh_xla(x);
          ull key = KOFF | ((ull)__float_as_uint(tv) << 32) |
                    (ull)(0xFFFFu - (gbase + jj));
          if (key > s0k) {
            double kd = __longlong_as_double((long long)key);
#pragma unroll
            for (int i = 0; i < KK - 1; ++i)
              s[i] = fmin(s[i + 1], fmax(s[i], kd));
            s[KK - 1] = fmax(s[KK - 1], kd);
            s0k = (ull)__double_as_longlong(s[0]);
          }
        }
      }
      if (sb < 16) mlo |= ((ull)nib) << (sb * 4);
      else         mhi |= ((ull)nib) << ((sb - 16) * 4);
    }

    float wv = 0.0f;
    int wi = 0;
    for (int r = 0; r < KK; ++r) {
      ull pk = KOFF;
      if (mlo | mhi) {
        int e = mlo ? __builtin_ctzll(mlo) : (64 + __builtin_ctzll(mhi));
        int pidx = ((e >> 2) << 8) + lane * 4 + (e & 3);
        pk = KOFF | RKEYHI | (ull)(0xFFFFu - (unsigned)pidx);
      }
      ull lk = (ull)__double_as_longlong(s[KK - 1]);
      bool fromList = lk > pk;
      ull cand = fromList ? lk : pk;
      ull win = cand;
#pragma unroll
      for (int d = 1; d < 64; d <<= 1) {
        ull o2 = shfl_xor_u64(win, d);
        win = (o2 > win) ? o2 : win;
      }
      if (win == KOFF) break;
      if (lane == r) {
        wv = __uint_as_float((unsigned)((win >> 32) & 0x3FFFFFFFu));
        wi = 0xFFFF - (int)(win & 0xFFFFull);
      }
      if (cand == win) {
        if (fromList) {
#pragma unroll
          for (int i = KK - 1; i > 0; --i) s[i] = s[i - 1];
          s[0] = EMPTYD;
        } else {
          if (mlo) mlo &= mlo - 1;
          else     mhi &= mhi - 1;
        }
      }
    }

    float4 z = make_float4(0.f, 0.f, 0.f, 0.f);
    for (int sb = 0; sb < 24; ++sb)
      *(float4*)(rp + (size_t)(sb * 64 + lane) * 4) = z;
    asm volatile("s_waitcnt vmcnt(0)" ::: "memory");
    if (wv > 0.0f) rp[wi] = wv;
  }
}

extern "C" void kernel_launch(void* const* d_in, const int* in_sizes, int n_in,
                              void* d_out, int out_size, void* d_ws, size_t ws_size,
                              hipStream_t stream) {
  const int*   idx       = (const int*)d_in[0];
  const float* scale_set = (const float*)d_in[2];
  const float* emb1      = (const float*)d_in[3];
  const float* emb2      = (const float*)d_in[4];
  const float* W1        = (const float*)d_in[5];
  const float* b1        = (const float*)d_in[6];
  const float* W2        = (const float*)d_in[7];
  const float* b2        = (const float*)d_in[8];
  float* out = (float*)d_out;

  const size_t VS = (size_t)NL * NN * DD;
  float* vt1 = (float*)d_ws;      // k-major [3][64][6144]
  float* vt2 = vt1 + VS;

  mlp_kernel<<<NN / MB, 256, 0, stream>>>(idx, scale_set, emb1, emb2, W1, b1, W2, b2,
                                          vt1, vt2);
  xmat_kernel<<<dim3(NN / BT2, NN / BT2, NL), 256, 0, stream>>>(vt1, vt2, out);
  topk_kernel<<<(NL * NN) / 4, 256, 0, stream>>>(out);
}

// Round 14
// 634.850 us; speedup vs baseline: 1.0375x; 1.0375x over previous
//
#include <hip/hip_runtime.h>
#include <hip/hip_bf16.h>

#define NN 6144
#define DD 64
#define NL 3
#define KK 24
#define BT2 128  // pair-tile dimension (xmat kernel)
#define KH2 16   // k-quarter staged at a time
#define MB 4     // rows per block (mlp kernel)
#define KCLAMP 7.99881172180175781f
#define BANDLO 7.0f   // x<=7.0 => tanh(x)<=1-1.66e-6; r(x)<=tanh+1e-6 < RB-7ulp

typedef unsigned long long ull;

// Bit-level emulation of XLA CPU f32 tanh, FMA variant. Verified bit-exact
// vs reference (rounds 2-13, absmax 0.0).
__device__ __forceinline__ float tanh_xla(float x) {
  float xc = fminf(fmaxf(x, -KCLAMP), KCLAMP);
  float x2 = xc * xc;
  float p = -2.76076847742355e-16f;
  p = fmaf(p, x2, 2.00018790482477e-13f);
  p = fmaf(p, x2, -8.60467152213735e-11f);
  p = fmaf(p, x2, 5.12229709037114e-08f);
  p = fmaf(p, x2, 1.48572235717979e-05f);
  p = fmaf(p, x2, 6.37261928875436e-04f);
  p = fmaf(p, x2, 4.89352455891786e-03f);
  p = xc * p;
  float q = 1.19825839466702e-06f;
  q = fmaf(q, x2, 1.18534705686654e-04f);
  q = fmaf(q, x2, 2.26843463243900e-03f);
  q = fmaf(q, x2, 4.89352518554385e-03f);
  float r = p / q;
  return (fabsf(x) < 0.0004f) ? x : r;
}

__device__ __forceinline__ ull shfl_xor_u64(ull v, int m) {
  unsigned lo = __shfl_xor((unsigned)v, m);
  unsigned hi = __shfl_xor((unsigned)(v >> 32), m);
  return ((ull)hi << 32) | lo;
}

// Kernel A: 3-layer tanh MLP chains (unchanged; bit-matches Eigen).
__global__ __launch_bounds__(256) void mlp_kernel(
    const int* __restrict__ idx, const float* __restrict__ scale_set,
    const float* __restrict__ emb1, const float* __restrict__ emb2,
    const float* __restrict__ W1, const float* __restrict__ b1,
    const float* __restrict__ W2, const float* __restrict__ b2,
    float* __restrict__ vt1, float* __restrict__ vt2) {
  __shared__ float Wt1[DD][DD];
  __shared__ float Wt2[DD][DD];
  __shared__ float bsh1[DD], bsh2[DD];
  __shared__ __align__(16) float o1sh[MB][DD];
  __shared__ __align__(16) float o2sh[MB][DD];
  const int t = threadIdx.x;
  const int r = t >> 6;
  const int j = t & 63;
  const int grow = blockIdx.x * MB + r;

  {
    int g = idx[grow];
    if (j < 16) {
      ((float4*)&o1sh[r][0])[j] = ((const float4*)(emb1 + (size_t)g * DD))[j];
      ((float4*)&o2sh[r][0])[j] = ((const float4*)(emb2 + (size_t)g * DD))[j];
    }
  }

  for (int l = 0; l < NL; ++l) {
    __syncthreads();
    {
      const float* w1p = W1 + ((size_t)l * DD + j) * DD + r * 16;
      const float* w2p = W2 + ((size_t)l * DD + j) * DD + r * 16;
#pragma unroll
      for (int w = 0; w < 4; ++w) {
        float4 a = *(const float4*)(w1p + 4 * w);
        float4 b = *(const float4*)(w2p + 4 * w);
        int k0 = r * 16 + 4 * w;
        Wt1[k0 + 0][j] = a.x; Wt1[k0 + 1][j] = a.y;
        Wt1[k0 + 2][j] = a.z; Wt1[k0 + 3][j] = a.w;
        Wt2[k0 + 0][j] = b.x; Wt2[k0 + 1][j] = b.y;
        Wt2[k0 + 2][j] = b.z; Wt2[k0 + 3][j] = b.w;
      }
    }
    if (t < DD) { bsh1[t] = b1[l * DD + t]; bsh2[t] = b2[l * DD + t]; }
    __syncthreads();

    const float s = scale_set[l];
    float a1 = 0.0f, a2 = 0.0f;
#pragma unroll
    for (int kb = 0; kb < 16; ++kb) {
      float4 s1 = ((const float4*)&o1sh[r][0])[kb];
      float4 s2 = ((const float4*)&o2sh[r][0])[kb];
      int k0 = 4 * kb;
      a1 = fmaf(s1.x * s, Wt1[k0 + 0][j], a1);
      a1 = fmaf(s1.y * s, Wt1[k0 + 1][j], a1);
      a1 = fmaf(s1.z * s, Wt1[k0 + 2][j], a1);
      a1 = fmaf(s1.w * s, Wt1[k0 + 3][j], a1);
      a2 = fmaf(s2.x * s, Wt2[k0 + 0][j], a2);
      a2 = fmaf(s2.y * s, Wt2[k0 + 1][j], a2);
      a2 = fmaf(s2.z * s, Wt2[k0 + 2][j], a2);
      a2 = fmaf(s2.w * s, Wt2[k0 + 3][j], a2);
    }
    float t1 = tanh_xla(3.0f * (a1 + bsh1[j]));
    float t2 = tanh_xla(3.0f * (a2 + bsh2[j]));
    __syncthreads();
    o1sh[r][j] = t1;
    o2sh[r][j] = t2;
    vt1[((size_t)l * DD + j) * NN + grow] = t1;
    vt2[((size_t)l * DD + j) * NN + grow] = t2;
  }
}

// Pass 1: antisymmetric pair-tile GEMM, 128x128 tile, 8x8 per-thread register
// tiles (unchanged from rounds 12-13; bit-exact mirror store).
__global__ __launch_bounds__(256) void xmat_kernel(
    const float* __restrict__ vt1, const float* __restrict__ vt2,
    float* __restrict__ out) {
  __shared__ float R1h[KH2][BT2];
  __shared__ float R2h[KH2][BT2];
  __shared__ float C1h[KH2][BT2];
  __shared__ float C2h[KH2][BT2];

  const int a = blockIdx.x;
  const int b = blockIdx.y;
  if (b < a) return;
  const int l = blockIdx.z;
  const int t = threadIdx.x;
  const int r0 = a * BT2;
  const int c0 = b * BT2;
  const float* w1 = vt1 + (size_t)l * DD * NN;
  const float* w2 = vt2 + (size_t)l * DD * NN;
  float* o = out + (size_t)l * NN * NN;

  const int ty = t >> 4;
  const int tx = t & 15;
  const int sk = t >> 4;
  const int sq = (t & 15) * 8;

  float acc1[8][8] = {{0.f}}, acc2[8][8] = {{0.f}};

#pragma unroll
  for (int h = 0; h < 4; ++h) {
    __syncthreads();
    {
      const size_t src = (size_t)(h * KH2 + sk) * NN;
      *(float4*)&R1h[sk][sq]     = *(const float4*)(w1 + src + r0 + sq);
      *(float4*)&R1h[sk][sq + 4] = *(const float4*)(w1 + src + r0 + sq + 4);
      *(float4*)&R2h[sk][sq]     = *(const float4*)(w2 + src + r0 + sq);
      *(float4*)&R2h[sk][sq + 4] = *(const float4*)(w2 + src + r0 + sq + 4);
      *(float4*)&C1h[sk][sq]     = *(const float4*)(w1 + src + c0 + sq);
      *(float4*)&C1h[sk][sq + 4] = *(const float4*)(w1 + src + c0 + sq + 4);
      *(float4*)&C2h[sk][sq]     = *(const float4*)(w2 + src + c0 + sq);
      *(float4*)&C2h[sk][sq + 4] = *(const float4*)(w2 + src + c0 + sq + 4);
    }
    __syncthreads();
#pragma unroll 2
    for (int kk = 0; kk < KH2; ++kk) {
      float r1[8], r2[8], c1[8], c2[8];
      *(float4*)&r1[0] = *(const float4*)&R1h[kk][8 * ty];
      *(float4*)&r1[4] = *(const float4*)&R1h[kk][8 * ty + 4];
      *(float4*)&r2[0] = *(const float4*)&R2h[kk][8 * ty];
      *(float4*)&r2[4] = *(const float4*)&R2h[kk][8 * ty + 4];
      *(float4*)&c1[0] = *(const float4*)&C1h[kk][8 * tx];
      *(float4*)&c1[4] = *(const float4*)&C1h[kk][8 * tx + 4];
      *(float4*)&c2[0] = *(const float4*)&C2h[kk][8 * tx];
      *(float4*)&c2[4] = *(const float4*)&C2h[kk][8 * tx + 4];
#pragma unroll
      for (int i = 0; i < 8; ++i)
#pragma unroll
        for (int j = 0; j < 8; ++j) {
          acc1[i][j] = fmaf(r1[i], c2[j], acc1[i][j]);  // v1_r . v2_c
          acc2[i][j] = fmaf(r2[i], c1[j], acc2[i][j]);  // v2_r . v1_c
        }
    }
  }

#pragma unroll
  for (int i = 0; i < 8; ++i) {
    float xv[8];
#pragma unroll
    for (int j = 0; j < 8; ++j) xv[j] = 3.0f * (acc1[i][j] - acc2[i][j]);
    float* p = o + (size_t)(r0 + 8 * ty + i) * NN + c0 + 8 * tx;
    *(float4*)p = *(float4*)&xv[0];
    *(float4*)(p + 4) = *(float4*)&xv[4];
  }
  if (b > a) {
#pragma unroll
    for (int j = 0; j < 8; ++j) {
      float xv[8];
#pragma unroll
      for (int i = 0; i < 8; ++i) xv[i] = 3.0f * (acc2[i][j] - acc1[i][j]);
      float* p = o + (size_t)(c0 + 8 * tx + j) * NN + r0 + 8 * ty;
      *(float4*)p = *(float4*)&xv[0];
      *(float4*)(p + 4) = *(float4*)&xv[4];
    }
  }
}

// Pass 2: one wave per row. ALL 24 float4 loads issued upfront (latency paid
// once, not 24x). Classify: plateau and band fold into 96-bit register masks
// (2 insts/element; no select chain, no overflow). Batch band eval re-loads
// the few band x-values from L2 via ffs loop, runs identical tanh_xla:
// ==RB joins RB masks, >RB becomes super (2 slots). Census -> early-breaking
// ballot ranking -> butterfly super extraction -> zero+scatter (verbatim
// round 13, validated). FALLBACK (wave-uniform: scnt>=3 or RB total < 24-S):
// round-9 full-list machinery (validated absmax 0.0).
__global__ __launch_bounds__(256, 2) void topk_kernel(float* __restrict__ out) {
  const int t = threadIdx.x;
  const int w = t >> 6;
  const int lane = t & 63;
  const int row = blockIdx.x * 4 + w;     // layer*NN + row
  float* rp = out + (size_t)row * NN;
  const float Rclamp = tanh_xla(8.0f);    // exact plateau value (clamp)
  const unsigned RB = __float_as_uint(Rclamp);
  const ull KOFF = 1ull << 62;
  const ull lmask = (1ull << lane) - 1;

  // Phase 1: issue all 24 loads upfront (static indices -> registers).
  float4 v[24];
#pragma unroll
  for (int sb = 0; sb < 24; ++sb)
    v[sb] = *(const float4*)(rp + (size_t)(sb * 64 + lane) * 4);

  // Phase 2: classify into 96-bit masks (plateau RB; band candidates).
  ull rblo = 0ull, rbhi = 0ull;
  ull bdlo = 0ull, bdhi = 0ull;
#pragma unroll
  for (int sb = 0; sb < 24; ++sb) {
    const float* xp = (const float*)&v[sb];
#pragma unroll
    for (int jj = 0; jj < 4; ++jj) {
      float x = xp[jj];
      bool pl = x >= KCLAMP;
      bool bd = (x > BANDLO) & !pl;
      if (sb < 16) {
        if (pl) rblo |= 1ull << (sb * 4 + jj);
        if (bd) bdlo |= 1ull << (sb * 4 + jj);
      } else {
        if (pl) rbhi |= 1ull << ((sb - 16) * 4 + jj);
        if (bd) bdhi |= 1ull << ((sb - 16) * 4 + jj);
      }
    }
  }

  // Phase 3: batch band evaluation (ffs loop; re-load x from L2-hot row).
  ull sup0 = 0ull, sup1 = 0ull;
  unsigned scnt = 0;
  {
    ull blo = bdlo, bhi = bdhi;
    while (__any((blo | bhi) != 0ull)) {
      bool has = (blo | bhi) != 0ull;
      int e = 0;
      if (has) e = blo ? __builtin_ctzll(blo) : 64 + __builtin_ctzll(bhi);
      int idx = (e >> 2) * 256 + lane * 4 + (e & 3);
      float x = has ? rp[idx] : 0.0f;
      unsigned vb = __float_as_uint(tanh_xla(x));
      if (has) {
        if (vb == RB) {
          if (e < 64) rblo |= 1ull << e;
          else        rbhi |= 1ull << (e - 64);
        } else if (vb > RB) {
          ull key = KOFF | ((ull)vb << 32) | (ull)(0xFFFFu - (unsigned)idx);
          if (scnt == 0u) sup0 = key;
          else if (scnt == 1u) sup1 = key;
          ++scnt;
        }
        if (blo) blo &= blo - 1;
        else     bhi &= bhi - 1;
      }
    }
  }

  // Super census (>2 on any lane -> fallback).
  bool fb = (__ballot(scnt >= 3u) != 0ull);
  ull bs1 = __ballot(scnt >= 1u);
  ull bs2 = __ballot(scnt >= 2u);
  unsigned S = (unsigned)__popcll(bs1) + (unsigned)__popcll(bs2);
  unsigned E = (S < 24u) ? S : 24u;
  unsigned C24 = 24u - E;

  // Ranking pass over RB masks (typically breaks after step 0).
  ull klo = 0ull, khi = 0ull;
  if (!fb && C24 > 0u) {
    unsigned cum = 0;
    for (int sb = 0; sb < 24; ++sb) {
      unsigned nib = (unsigned)((sb < 16 ? (rblo >> (sb * 4))
                                         : (rbhi >> ((sb - 16) * 4))) & 15ull);
      ull bl0 = __ballot((nib & 1u) != 0u);
      ull bl1 = __ballot((nib & 2u) != 0u);
      ull bl2 = __ballot((nib & 4u) != 0u);
      ull bl3 = __ballot((nib & 8u) != 0u);
      unsigned below = (unsigned)__popcll(bl0 & lmask) +
                       (unsigned)__popcll(bl1 & lmask) +
                       (unsigned)__popcll(bl2 & lmask) +
                       (unsigned)__popcll(bl3 & lmask);
      unsigned base = cum + below;
#pragma unroll
      for (int jj = 0; jj < 4; ++jj) {
        if (nib & (1u << jj)) {
          unsigned rk = base + (unsigned)__builtin_popcount(nib & ((1u << jj) - 1u));
          if (rk < C24) {
            if (sb < 16) klo |= 1ull << (sb * 4 + jj);
            else         khi |= 1ull << ((sb - 16) * 4 + jj);
          }
        }
      }
      cum += (unsigned)__popcll(bl0) + (unsigned)__popcll(bl1) +
             (unsigned)__popcll(bl2) + (unsigned)__popcll(bl3);
      if (cum >= C24) break;   // wave-uniform; later ranks can't qualify
    }
    if (cum < C24) fb = true;  // not enough RB-class -> sub-RB would matter
  }

  if (!fb) {
    // Extract supers: e-th winner parked in lane e.
    float wv = 0.0f;
    int wi = 0;
    for (unsigned e = 0; e < E; ++e) {
      ull cand = (sup0 > sup1) ? sup0 : sup1;
      ull win = cand;
#pragma unroll
      for (int d = 1; d < 64; d <<= 1) {
        ull o2 = shfl_xor_u64(win, d);
        win = (o2 > win) ? o2 : win;
      }
      if (lane == (int)e) {
        wv = __uint_as_float((unsigned)((win >> 32) & 0x3FFFFFFFu));
        wi = 0xFFFF - (int)(win & 0xFFFFull);
      }
      if (sup0 == win) sup0 = 0ull;
      else if (sup1 == win) sup1 = 0ull;
    }
    // Zero the row, drain, scatter RB winners (Rclamp) + supers (own value).
    float4 z = make_float4(0.f, 0.f, 0.f, 0.f);
    for (int sb = 0; sb < 24; ++sb)
      *(float4*)(rp + (size_t)(sb * 64 + lane) * 4) = z;
    asm volatile("s_waitcnt vmcnt(0)" ::: "memory");
    while (klo) {
      int e = __builtin_ctzll(klo);
      rp[(e >> 2) * 256 + lane * 4 + (e & 3)] = Rclamp;
      klo &= klo - 1;
    }
    while (khi) {
      int e = __builtin_ctzll(khi);
      rp[(16 + (e >> 2)) * 256 + lane * 4 + (e & 3)] = Rclamp;
      khi &= khi - 1;
    }
    if (lane < (int)E && wv > 0.0f) rp[wi] = wv;
    return;
  }

  // FALLBACK: round-9 full-list scan + merge extraction (exact, validated).
  {
    const ull RKEYHI = (ull)RB << 32;
    const double EMPTYD = __longlong_as_double((long long)KOFF);
    ull mlo = 0ull, mhi = 0ull;   // plateau (x>=clamp) slot masks
    double s[KK];
#pragma unroll
    for (int q = 0; q < KK; ++q) s[q] = EMPTYD;
    ull s0k = KOFF;

    for (int sb = 0; sb < 24; ++sb) {
      float4 x4 = *(const float4*)(rp + (size_t)(sb * 64 + lane) * 4);
      const float* xp = (const float*)&x4;
      const unsigned gbase = (unsigned)(sb * 256 + lane * 4);
      unsigned nib = 0u;
#pragma unroll
      for (int jj = 0; jj < 4; ++jj) {
        float x = xp[jj];
        if (x >= KCLAMP) {
          nib |= 1u << jj;
        } else if (x > 0.0f) {
          float tv = tanh_xla(x);
          ull key = KOFF | ((ull)__float_as_uint(tv) << 32) |
                    (ull)(0xFFFFu - (gbase + jj));
          if (key > s0k) {
            double kd = __longlong_as_double((long long)key);
#pragma unroll
            for (int i = 0; i < KK - 1; ++i)
              s[i] = fmin(s[i + 1], fmax(s[i], kd));
            s[KK - 1] = fmax(s[KK - 1], kd);
            s0k = (ull)__double_as_longlong(s[0]);
          }
        }
      }
      if (sb < 16) mlo |= ((ull)nib) << (sb * 4);
      else         mhi |= ((ull)nib) << ((sb - 16) * 4);
    }

    float wv = 0.0f;
    int wi = 0;
    for (int r = 0; r < KK; ++r) {
      ull pk = KOFF;
      if (mlo | mhi) {
        int e = mlo ? __builtin_ctzll(mlo) : (64 + __builtin_ctzll(mhi));
        int pidx = ((e >> 2) << 8) + lane * 4 + (e & 3);
        pk = KOFF | RKEYHI | (ull)(0xFFFFu - (unsigned)pidx);
      }
      ull lk = (ull)__double_as_longlong(s[KK - 1]);
      bool fromList = lk > pk;
      ull cand = fromList ? lk : pk;
      ull win = cand;
#pragma unroll
      for (int d = 1; d < 64; d <<= 1) {
        ull o2 = shfl_xor_u64(win, d);
        win = (o2 > win) ? o2 : win;
      }
      if (win == KOFF) break;
      if (lane == r) {
        wv = __uint_as_float((unsigned)((win >> 32) & 0x3FFFFFFFu));
        wi = 0xFFFF - (int)(win & 0xFFFFull);
      }
      if (cand == win) {
        if (fromList) {
#pragma unroll
          for (int i = KK - 1; i > 0; --i) s[i] = s[i - 1];
          s[0] = EMPTYD;
        } else {
          if (mlo) mlo &= mlo - 1;
          else     mhi &= mhi - 1;
        }
      }
    }

    float4 z = make_float4(0.f, 0.f, 0.f, 0.f);
    for (int sb = 0; sb < 24; ++sb)
      *(float4*)(rp + (size_t)(sb * 64 + lane) * 4) = z;
    asm volatile("s_waitcnt vmcnt(0)" ::: "memory");
    if (wv > 0.0f) rp[wi] = wv;
  }
}

extern "C" void kernel_launch(void* const* d_in, const int* in_sizes, int n_in,
                              void* d_out, int out_size, void* d_ws, size_t ws_size,
                              hipStream_t stream) {
  const int*   idx       = (const int*)d_in[0];
  const float* scale_set = (const float*)d_in[2];
  const float* emb1      = (const float*)d_in[3];
  const float* emb2      = (const float*)d_in[4];
  const float* W1        = (const float*)d_in[5];
  const float* b1        = (const float*)d_in[6];
  const float* W2        = (const float*)d_in[7];
  const float* b2        = (const float*)d_in[8];
  float* out = (float*)d_out;

  const size_t VS = (size_t)NL * NN * DD;
  float* vt1 = (float*)d_ws;      // k-major [3][64][6144]
  float* vt2 = vt1 + VS;

  mlp_kernel<<<NN / MB, 256, 0, stream>>>(idx, scale_set, emb1, emb2, W1, b1, W2, b2,
                                          vt1, vt2);
  xmat_kernel<<<dim3(NN / BT2, NN / BT2, NL), 256, 0, stream>>>(vt1, vt2, out);
  topk_kernel<<<(NL * NN) / 4, 256, 0, stream>>>(out);
}

// Round 15
// 630.466 us; speedup vs baseline: 1.0447x; 1.0070x over previous
//
#include <hip/hip_runtime.h>
#include <hip/hip_bf16.h>

#define NN 6144
#define DD 64
#define NL 3
#define KK 24
#define BT2 128  // pair-tile dimension (xmat kernel)
#define KH2 16   // k-quarter staged at a time
#define MB 4     // rows per block (mlp kernel)
#define KCLAMP 7.99881172180175781f
#define BANDLO 7.0f   // x<=7.0 => r(x) < RB provably (validated rounds 13-14)

typedef unsigned long long ull;

// Bit-level emulation of XLA CPU f32 tanh, FMA variant. Verified bit-exact
// vs reference (rounds 2-14, absmax 0.0).
__device__ __forceinline__ float tanh_xla(float x) {
  float xc = fminf(fmaxf(x, -KCLAMP), KCLAMP);
  float x2 = xc * xc;
  float p = -2.76076847742355e-16f;
  p = fmaf(p, x2, 2.00018790482477e-13f);
  p = fmaf(p, x2, -8.60467152213735e-11f);
  p = fmaf(p, x2, 5.12229709037114e-08f);
  p = fmaf(p, x2, 1.48572235717979e-05f);
  p = fmaf(p, x2, 6.37261928875436e-04f);
  p = fmaf(p, x2, 4.89352455891786e-03f);
  p = xc * p;
  float q = 1.19825839466702e-06f;
  q = fmaf(q, x2, 1.18534705686654e-04f);
  q = fmaf(q, x2, 2.26843463243900e-03f);
  q = fmaf(q, x2, 4.89352518554385e-03f);
  float r = p / q;
  return (fabsf(x) < 0.0004f) ? x : r;
}

__device__ __forceinline__ ull shfl_xor_u64(ull v, int m) {
  unsigned lo = __shfl_xor((unsigned)v, m);
  unsigned hi = __shfl_xor((unsigned)(v >> 32), m);
  return ((ull)hi << 32) | lo;
}

// Kernel A: 3-layer tanh MLP chains (bit-matches Eigen). Also zeroes the
// per-row super counters (must be re-zeroed every launch for graph replay).
__global__ __launch_bounds__(256) void mlp_kernel(
    const int* __restrict__ idx, const float* __restrict__ scale_set,
    const float* __restrict__ emb1, const float* __restrict__ emb2,
    const float* __restrict__ W1, const float* __restrict__ b1,
    const float* __restrict__ W2, const float* __restrict__ b2,
    float* __restrict__ vt1, float* __restrict__ vt2,
    unsigned* __restrict__ supercnt) {
  __shared__ float Wt1[DD][DD];
  __shared__ float Wt2[DD][DD];
  __shared__ float bsh1[DD], bsh2[DD];
  __shared__ __align__(16) float o1sh[MB][DD];
  __shared__ __align__(16) float o2sh[MB][DD];
  const int t = threadIdx.x;
  const int r = t >> 6;
  const int j = t & 63;
  const int grow = blockIdx.x * MB + r;

  if (t < 12) supercnt[blockIdx.x * 12 + t] = 0u;   // 1536*12 = NL*NN

  {
    int g = idx[grow];
    if (j < 16) {
      ((float4*)&o1sh[r][0])[j] = ((const float4*)(emb1 + (size_t)g * DD))[j];
      ((float4*)&o2sh[r][0])[j] = ((const float4*)(emb2 + (size_t)g * DD))[j];
    }
  }

  for (int l = 0; l < NL; ++l) {
    __syncthreads();
    {
      const float* w1p = W1 + ((size_t)l * DD + j) * DD + r * 16;
      const float* w2p = W2 + ((size_t)l * DD + j) * DD + r * 16;
#pragma unroll
      for (int w = 0; w < 4; ++w) {
        float4 a = *(const float4*)(w1p + 4 * w);
        float4 b = *(const float4*)(w2p + 4 * w);
        int k0 = r * 16 + 4 * w;
        Wt1[k0 + 0][j] = a.x; Wt1[k0 + 1][j] = a.y;
        Wt1[k0 + 2][j] = a.z; Wt1[k0 + 3][j] = a.w;
        Wt2[k0 + 0][j] = b.x; Wt2[k0 + 1][j] = b.y;
        Wt2[k0 + 2][j] = b.z; Wt2[k0 + 3][j] = b.w;
      }
    }
    if (t < DD) { bsh1[t] = b1[l * DD + t]; bsh2[t] = b2[l * DD + t]; }
    __syncthreads();

    const float s = scale_set[l];
    float a1 = 0.0f, a2 = 0.0f;
#pragma unroll
    for (int kb = 0; kb < 16; ++kb) {
      float4 s1 = ((const float4*)&o1sh[r][0])[kb];
      float4 s2 = ((const float4*)&o2sh[r][0])[kb];
      int k0 = 4 * kb;
      a1 = fmaf(s1.x * s, Wt1[k0 + 0][j], a1);
      a1 = fmaf(s1.y * s, Wt1[k0 + 1][j], a1);
      a1 = fmaf(s1.z * s, Wt1[k0 + 2][j], a1);
      a1 = fmaf(s1.w * s, Wt1[k0 + 3][j], a1);
      a2 = fmaf(s2.x * s, Wt2[k0 + 0][j], a2);
      a2 = fmaf(s2.y * s, Wt2[k0 + 1][j], a2);
      a2 = fmaf(s2.z * s, Wt2[k0 + 2][j], a2);
      a2 = fmaf(s2.w * s, Wt2[k0 + 3][j], a2);
    }
    float t1 = tanh_xla(3.0f * (a1 + bsh1[j]));
    float t2 = tanh_xla(3.0f * (a2 + bsh2[j]));
    __syncthreads();
    o1sh[r][j] = t1;
    o2sh[r][j] = t2;
    vt1[((size_t)l * DD + j) * NN + grow] = t1;
    vt2[((size_t)l * DD + j) * NN + grow] = t2;
  }
}

// Pass 1: antisymmetric pair-tile GEMM (validated chains; bit-exact mirror).
// NEW: classifies every element in-register (plateau / band-tanh) and emits
// per-(row, 128col-tile) 128-bit RB bitmaps + per-row super records, so the
// topk pass never re-reads the 453MB x matrix. x still stored (fallback src).
__global__ __launch_bounds__(256) void xmat_kernel(
    const float* __restrict__ vt1, const float* __restrict__ vt2,
    float* __restrict__ out, ulonglong2* __restrict__ pb,
    unsigned* __restrict__ supercnt, uint2* __restrict__ superrec) {
  __shared__ float R1h[KH2][BT2];
  __shared__ float R2h[KH2][BT2];
  __shared__ float C1h[KH2][BT2];
  __shared__ float C2h[KH2][BT2];

  const int a = blockIdx.x;
  const int b = blockIdx.y;
  if (b < a) return;
  const int l = blockIdx.z;
  const int t = threadIdx.x;
  const int r0 = a * BT2;
  const int c0 = b * BT2;
  const float* w1 = vt1 + (size_t)l * DD * NN;
  const float* w2 = vt2 + (size_t)l * DD * NN;
  float* o = out + (size_t)l * NN * NN;
  const unsigned RB = __float_as_uint(tanh_xla(8.0f));  // plateau value bits

  const int ty = t >> 4;
  const int tx = t & 15;
  const int sk = t >> 4;
  const int sq = (t & 15) * 8;

  float acc1[8][8] = {{0.f}}, acc2[8][8] = {{0.f}};

#pragma unroll
  for (int h = 0; h < 4; ++h) {
    __syncthreads();
    {
      const size_t src = (size_t)(h * KH2 + sk) * NN;
      *(float4*)&R1h[sk][sq]     = *(const float4*)(w1 + src + r0 + sq);
      *(float4*)&R1h[sk][sq + 4] = *(const float4*)(w1 + src + r0 + sq + 4);
      *(float4*)&R2h[sk][sq]     = *(const float4*)(w2 + src + r0 + sq);
      *(float4*)&R2h[sk][sq + 4] = *(const float4*)(w2 + src + r0 + sq + 4);
      *(float4*)&C1h[sk][sq]     = *(const float4*)(w1 + src + c0 + sq);
      *(float4*)&C1h[sk][sq + 4] = *(const float4*)(w1 + src + c0 + sq + 4);
      *(float4*)&C2h[sk][sq]     = *(const float4*)(w2 + src + c0 + sq);
      *(float4*)&C2h[sk][sq + 4] = *(const float4*)(w2 + src + c0 + sq + 4);
    }
    __syncthreads();
#pragma unroll 2
    for (int kk = 0; kk < KH2; ++kk) {
      float r1[8], r2[8], c1[8], c2[8];
      *(float4*)&r1[0] = *(const float4*)&R1h[kk][8 * ty];
      *(float4*)&r1[4] = *(const float4*)&R1h[kk][8 * ty + 4];
      *(float4*)&r2[0] = *(const float4*)&R2h[kk][8 * ty];
      *(float4*)&r2[4] = *(const float4*)&R2h[kk][8 * ty + 4];
      *(float4*)&c1[0] = *(const float4*)&C1h[kk][8 * tx];
      *(float4*)&c1[4] = *(const float4*)&C1h[kk][8 * tx + 4];
      *(float4*)&c2[0] = *(const float4*)&C2h[kk][8 * tx];
      *(float4*)&c2[4] = *(const float4*)&C2h[kk][8 * tx + 4];
#pragma unroll
      for (int i = 0; i < 8; ++i)
#pragma unroll
        for (int j = 0; j < 8; ++j) {
          acc1[i][j] = fmaf(r1[i], c2[j], acc1[i][j]);  // v1_r . v2_c
          acc2[i][j] = fmaf(r2[i], c1[j], acc2[i][j]);  // v2_r . v1_c
        }
    }
  }

  __syncthreads();   // staging LDS dead -> overlay nibble buffers on C1h
  unsigned char* nibD = (unsigned char*)&C1h[0][0];         // [128][16]
  unsigned char* nibM = ((unsigned char*)&C1h[0][0]) + 2048;

  // Direct tile: store x + classify (plateau || band==RB -> bit; band>RB ->
  // super append). Identical x expression / tanh bits as validated topk.
#pragma unroll
  for (int i = 0; i < 8; ++i) {
    float xv[8];
    unsigned bits = 0;
#pragma unroll
    for (int j = 0; j < 8; ++j) {
      float x = 3.0f * (acc1[i][j] - acc2[i][j]);
      xv[j] = x;
      bool rb = (x >= KCLAMP);
      if (!rb && x > BANDLO) {
        unsigned vb = __float_as_uint(tanh_xla(x));
        if (vb == RB) rb = true;
        else if (vb > RB) {
          size_t grow = (size_t)l * NN + (r0 + 8 * ty + i);
          unsigned slot = atomicAdd(&supercnt[grow], 1u);
          if (slot < 8u)
            superrec[grow * 8 + slot] = make_uint2(vb, (unsigned)(c0 + 8 * tx + j));
        }
      }
      if (rb) bits |= 1u << j;
    }
    float* p = o + (size_t)(r0 + 8 * ty + i) * NN + c0 + 8 * tx;
    *(float4*)p = *(float4*)&xv[0];
    *(float4*)(p + 4) = *(float4*)&xv[4];
    nibD[(8 * ty + i) * 16 + tx] = (unsigned char)bits;
  }
  // Mirror tile (b>a): mirror x = 3*(acc2-acc1) bitwise; same classification.
  if (b > a) {
#pragma unroll
    for (int j = 0; j < 8; ++j) {
      float xv[8];
      unsigned bits = 0;
#pragma unroll
      for (int i = 0; i < 8; ++i) {
        float x = 3.0f * (acc2[i][j] - acc1[i][j]);
        xv[i] = x;
        bool rb = (x >= KCLAMP);
        if (!rb && x > BANDLO) {
          unsigned vb = __float_as_uint(tanh_xla(x));
          if (vb == RB) rb = true;
          else if (vb > RB) {
            size_t grow = (size_t)l * NN + (c0 + 8 * tx + j);
            unsigned slot = atomicAdd(&supercnt[grow], 1u);
            if (slot < 8u)
              superrec[grow * 8 + slot] = make_uint2(vb, (unsigned)(r0 + 8 * ty + i));
          }
        }
        if (rb) bits |= 1u << i;
      }
      float* p = o + (size_t)(c0 + 8 * tx + j) * NN + r0 + 8 * ty;
      *(float4*)p = *(float4*)&xv[0];
      *(float4*)(p + 4) = *(float4*)&xv[4];
      nibM[(8 * tx + j) * 16 + ty] = (unsigned char)bits;
    }
  }
  __syncthreads();
  // Fold nibbles -> 128-bit bitmaps (one thread per row). Each (row,tile)
  // is written by exactly one block (direct for i<=j pairs, mirror for i>j).
  if (t < 128) {
    uint4 q = *(const uint4*)&nibD[t * 16];
    ull lo = (ull)q.x | ((ull)q.y << 32);
    ull hi = (ull)q.z | ((ull)q.w << 32);
    pb[((size_t)l * NN + r0 + t) * 48 + b] = make_ulonglong2(lo, hi);
    if (b > a) {
      uint4 m = *(const uint4*)&nibM[t * 16];
      ull mlo = (ull)m.x | ((ull)m.y << 32);
      ull mhi = (ull)m.z | ((ull)m.w << 32);
      pb[((size_t)l * NN + c0 + t) * 48 + a] = make_ulonglong2(mlo, mhi);
    }
  }
}

// Pass 2: one wave per row, selection from bitmaps (no x re-read).
// Winners = S supers (value desc, idx asc) + first (24-S) RB-class bits by
// ascending index (prefix-sum rank over 48 tile-lanes). Zero row + scatter.
// FALLBACK (wave-uniform: S>8 or total RB < 24-S): round-9 full-list
// machinery reading the materialized x row (validated absmax 0.0).
__global__ __launch_bounds__(256, 2) void topk_kernel(
    const ulonglong2* __restrict__ pb, const unsigned* __restrict__ supercnt,
    const uint2* __restrict__ superrec, float* __restrict__ out) {
  const int t = threadIdx.x;
  const int w = t >> 6;
  const int lane = t & 63;
  const int row = blockIdx.x * 4 + w;     // layer*NN + row
  float* rp = out + (size_t)row * NN;
  const float Rclamp = tanh_xla(8.0f);
  const unsigned RB = __float_as_uint(Rclamp);
  const ull KOFF = 1ull << 62;

  ull bmx = 0ull, bmy = 0ull;
  if (lane < 48) {
    ulonglong2 bmv = pb[(size_t)row * 48 + lane];
    bmx = bmv.x; bmy = bmv.y;
  }
  const unsigned S = supercnt[row];       // wave-uniform
  bool fb = (S > 8u);
  const unsigned E = (S < 24u) ? S : 24u;
  const unsigned C24 = 24u - E;

  ull skey = 0ull;
  if (!fb && lane < (int)S) {
    uint2 rec = superrec[(size_t)row * 8 + lane];
    skey = KOFF | ((ull)rec.x << 32) | (ull)(0xFFFFu - rec.y);
  }

  // Rank RB bits: exclusive prefix of per-tile popcounts across lanes.
  unsigned cnt = (unsigned)__popcll(bmx) + (unsigned)__popcll(bmy);
  unsigned p = cnt;
#pragma unroll
  for (int d = 1; d < 64; d <<= 1) {
    unsigned o2 = __shfl_up(p, d);
    if (lane >= d) p += o2;
  }
  unsigned excl = p - cnt;
  unsigned total = __shfl(p, 63);
  if (total < C24) fb = true;             // wave-uniform

  if (!fb) {
    // Extract supers: e-th winner parked in lane e (keys unique).
    float wv = 0.0f;
    int wi = 0;
    for (unsigned e = 0; e < E; ++e) {
      ull win = skey;
#pragma unroll
      for (int d = 1; d < 64; d <<= 1) {
        ull o2 = shfl_xor_u64(win, d);
        win = (o2 > win) ? o2 : win;
      }
      if (lane == (int)e) {
        wv = __uint_as_float((unsigned)((win >> 32) & 0x3FFFFFFFu));
        wi = 0xFFFF - (int)(win & 0xFFFFull);
      }
      if (skey == win) skey = 0ull;
    }
    // Zero the row, drain all wave stores, then scatter.
    float4 z = make_float4(0.f, 0.f, 0.f, 0.f);
    for (int sb = 0; sb < 24; ++sb)
      *(float4*)(rp + (size_t)(sb * 64 + lane) * 4) = z;
    asm volatile("s_waitcnt vmcnt(0)" ::: "memory");
    int need = (int)C24 - (int)excl;
    if (need > (int)cnt) need = (int)cnt;
    if (need > 0 && lane < 48) {
      int base = lane * 128;
      int done = 0;
      ull m = bmx;
      while (done < need && m) {
        int k = __builtin_ctzll(m);
        rp[base + k] = Rclamp;
        m &= m - 1; ++done;
      }
      m = bmy;
      while (done < need && m) {
        int k = __builtin_ctzll(m);
        rp[base + 64 + k] = Rclamp;
        m &= m - 1; ++done;
      }
    }
    if (lane < (int)E && wv > 0.0f) rp[wi] = wv;
    return;
  }

  // FALLBACK: round-9 full-list scan + merge extraction over the
  // materialized x row (exact, validated).
  {
    const ull RKEYHI = (ull)RB << 32;
    const double EMPTYD = __longlong_as_double((long long)KOFF);
    ull mlo = 0ull, mhi = 0ull;
    double s[KK];
#pragma unroll
    for (int q = 0; q < KK; ++q) s[q] = EMPTYD;
    ull s0k = KOFF;

    for (int sb = 0; sb < 24; ++sb) {
      float4 x4 = *(const float4*)(rp + (size_t)(sb * 64 + lane) * 4);
      const float* xp = (const float*)&x4;
      const unsigned gbase = (unsigned)(sb * 256 + lane * 4);
      unsigned nib = 0u;
#pragma unroll
      for (int jj = 0; jj < 4; ++jj) {
        float x = xp[jj];
        if (x >= KCLAMP) {
          nib |= 1u << jj;
        } else if (x > 0.0f) {
          float tv = tanh_xla(x);
          ull key = KOFF | ((ull)__float_as_uint(tv) << 32) |
                    (ull)(0xFFFFu - (gbase + jj));
          if (key > s0k) {
            double kd = __longlong_as_double((long long)key);
#pragma unroll
            for (int i = 0; i < KK - 1; ++i)
              s[i] = fmin(s[i + 1], fmax(s[i], kd));
            s[KK - 1] = fmax(s[KK - 1], kd);
            s0k = (ull)__double_as_longlong(s[0]);
          }
        }
      }
      if (sb < 16) mlo |= ((ull)nib) << (sb * 4);
      else         mhi |= ((ull)nib) << ((sb - 16) * 4);
    }

    float wv = 0.0f;
    int wi = 0;
    for (int r = 0; r < KK; ++r) {
      ull pk = KOFF;
      if (mlo | mhi) {
        int e = mlo ? __builtin_ctzll(mlo) : (64 + __builtin_ctzll(mhi));
        int pidx = ((e >> 2) << 8) + lane * 4 + (e & 3);
        pk = KOFF | RKEYHI | (ull)(0xFFFFu - (unsigned)pidx);
      }
      ull lk = (ull)__double_as_longlong(s[KK - 1]);
      bool fromList = lk > pk;
      ull cand = fromList ? lk : pk;
      ull win = cand;
#pragma unroll
      for (int d = 1; d < 64; d <<= 1) {
        ull o2 = shfl_xor_u64(win, d);
        win = (o2 > win) ? o2 : win;
      }
      if (win == KOFF) break;
      if (lane == r) {
        wv = __uint_as_float((unsigned)((win >> 32) & 0x3FFFFFFFu));
        wi = 0xFFFF - (int)(win & 0xFFFFull);
      }
      if (cand == win) {
        if (fromList) {
#pragma unroll
          for (int i = KK - 1; i > 0; --i) s[i] = s[i - 1];
          s[0] = EMPTYD;
        } else {
          if (mlo) mlo &= mlo - 1;
          else     mhi &= mhi - 1;
        }
      }
    }

    float4 z = make_float4(0.f, 0.f, 0.f, 0.f);
    for (int sb = 0; sb < 24; ++sb)
      *(float4*)(rp + (size_t)(sb * 64 + lane) * 4) = z;
    asm volatile("s_waitcnt vmcnt(0)" ::: "memory");
    if (wv > 0.0f) rp[wi] = wv;
  }
}

extern "C" void kernel_launch(void* const* d_in, const int* in_sizes, int n_in,
                              void* d_out, int out_size, void* d_ws, size_t ws_size,
                              hipStream_t stream) {
  const int*   idx       = (const int*)d_in[0];
  const float* scale_set = (const float*)d_in[2];
  const float* emb1      = (const float*)d_in[3];
  const float* emb2      = (const float*)d_in[4];
  const float* W1        = (const float*)d_in[5];
  const float* b1        = (const float*)d_in[6];
  const float* W2        = (const float*)d_in[7];
  const float* b2        = (const float*)d_in[8];
  float* out = (float*)d_out;

  const size_t VS = (size_t)NL * NN * DD;
  float* vt1 = (float*)d_ws;                         // 4.7 MB
  float* vt2 = vt1 + VS;                             // 4.7 MB
  ulonglong2* pb = (ulonglong2*)(vt2 + VS);          // [NL*NN][48] = 14.2 MB
  unsigned* supercnt = (unsigned*)(pb + (size_t)NL * NN * 48);  // 74 KB
  uint2* superrec = (uint2*)(supercnt + (size_t)NL * NN);       // 1.2 MB

  mlp_kernel<<<NN / MB, 256, 0, stream>>>(idx, scale_set, emb1, emb2, W1, b1, W2, b2,
                                          vt1, vt2, supercnt);
  xmat_kernel<<<dim3(NN / BT2, NN / BT2, NL), 256, 0, stream>>>(
      vt1, vt2, out, pb, supercnt, superrec);
  topk_kernel<<<(NL * NN) / 4, 256, 0, stream>>>(pb, supercnt, superrec, out);
}